// Round 1
// baseline (1052.082 us; speedup 1.0000x reference)
//
#include <hip/hip_runtime.h>
#include <hip/hip_bf16.h>

typedef __hip_bfloat16 bf16;

// Problem constants (from setup_inputs): B=64, n=m=14, E=512, D1=1024, heads=8
constexpr int NB    = 64;
constexpr int NN    = 14;
constexpr int MM    = 14;
constexpr int EE    = 512;
constexpr int DD1   = 1024;
constexpr int RR    = 27;            // 2n-1
constexpr int RPOS  = RR * RR;       // 729
constexpr int ROWS  = NB * NN * MM;  // 12544

#define RMS_EPS 1e-6f
#define GAMMA_LOG2 (-0.00144344319f)   // log2(0.999)

__device__ __forceinline__ float ldf(const float* p)  { return *p; }
__device__ __forceinline__ float ldf(const bf16* p)   { return __bfloat162float(*p); }
__device__ __forceinline__ void  stf(float* p, float v) { *p = v; }
__device__ __forceinline__ void  stf(bf16* p, float v)  { *p = __float2bfloat16(v); }

// ---------------------------------------------------------------------------
// r0[p][c] = ii * w[0][c] + jj * w[1][c] + b[c], p in [0,729), c in [0,512)
__global__ void k_rpe_pos(const float* __restrict__ w, const float* __restrict__ bias,
                          float* __restrict__ out) {
    int p = blockIdx.x;
    float ii = (float)(p / 27 - 13);
    float jj = (float)(p % 27 - 13);
    for (int c = threadIdx.x; c < 512; c += 256)
        out[p * 512 + c] = ii * w[c] + jj * w[512 + c] + bias[c];
}

// ---------------------------------------------------------------------------
// out[r][:] = relu(in[r][:] * rsqrt(mean(in[r]^2) + eps)), 512 cols
__global__ void k_rmsnorm_relu(const float* __restrict__ in, float* __restrict__ out) {
    int r = blockIdx.x;
    const float* x = in + (size_t)r * 512;
    float v0 = x[threadIdx.x];
    float v1 = x[threadIdx.x + 256];
    float s = v0 * v0 + v1 * v1;
    #pragma unroll
    for (int off = 32; off; off >>= 1) s += __shfl_down(s, off, 64);
    __shared__ float ps[4];
    if ((threadIdx.x & 63) == 0) ps[threadIdx.x >> 6] = s;
    __syncthreads();
    float tot = ps[0] + ps[1] + ps[2] + ps[3];
    float scale = rsqrtf(tot * (1.0f / 512.0f) + RMS_EPS);
    out[(size_t)r * 512 + threadIdx.x]       = fmaxf(v0 * scale, 0.0f);
    out[(size_t)r * 512 + threadIdx.x + 256] = fmaxf(v1 * scale, 0.0f);
}

// ---------------------------------------------------------------------------
// Generic tiled fp32 GEMM: out = epi(A[Mr x Kd] @ Bw[Kd x Nc] + bias)
// EPI: 0 = none, 1 = silu, 2 = Toeplitz decay gamma^(|i-13|+|j-13|) by row
// BM=BN=64, BK=16, 256 threads, 4x4 micro-tile.
template <typename TA, int EPI, typename TO>
__global__ __launch_bounds__(256) void k_gemm(const TA* __restrict__ A,
                                              const float* __restrict__ Bw,
                                              const float* __restrict__ bias,
                                              TO* __restrict__ out,
                                              int Mr, int Nc, int Kd) {
    __shared__ float As[16][64];
    __shared__ float Bs[16][64];
    const int m0 = blockIdx.y * 64;
    const int n0 = blockIdx.x * 64;
    const int tid = threadIdx.x;
    const int tr = tid >> 4;   // 0..15
    const int tc = tid & 15;   // 0..15

    float acc[4][4] = {};

    for (int k0 = 0; k0 < Kd; k0 += 16) {
        #pragma unroll
        for (int l = 0; l < 4; ++l) {
            int idx = tid + l * 256;          // 0..1023
            int m = idx >> 4, k = idx & 15;
            int gm = m0 + m;
            float val = (gm < Mr) ? ldf(&A[(size_t)gm * Kd + k0 + k]) : 0.0f;
            As[k][m] = val;
        }
        #pragma unroll
        for (int l = 0; l < 4; ++l) {
            int idx = tid + l * 256;
            int k = idx >> 6, n = idx & 63;
            Bs[k][n] = Bw[(size_t)(k0 + k) * Nc + n0 + n];
        }
        __syncthreads();
        #pragma unroll
        for (int kk = 0; kk < 16; ++kk) {
            float4 a4 = *(const float4*)&As[kk][tr * 4];
            float4 b4 = *(const float4*)&Bs[kk][tc * 4];
            float av[4] = {a4.x, a4.y, a4.z, a4.w};
            float bv[4] = {b4.x, b4.y, b4.z, b4.w};
            #pragma unroll
            for (int r = 0; r < 4; ++r)
                #pragma unroll
                for (int c = 0; c < 4; ++c)
                    acc[r][c] = fmaf(av[r], bv[c], acc[r][c]);
        }
        __syncthreads();
    }

    #pragma unroll
    for (int r = 0; r < 4; ++r) {
        int row = m0 + tr * 4 + r;
        if (row >= Mr) break;
        float decay = 1.0f;
        if (EPI == 2) {
            int i = row / 27, j = row % 27;
            float dist = (float)(abs(i - 13) + abs(j - 13));
            decay = exp2f(dist * GAMMA_LOG2);
        }
        #pragma unroll
        for (int c = 0; c < 4; ++c) {
            int col = n0 + tc * 4 + c;
            float val = acc[r][c] + bias[col];
            if (EPI == 1) val = val / (1.0f + expf(-val));
            if (EPI == 2) val *= decay;
            stf(&out[(size_t)row * Nc + col], val);
        }
    }
}

// ---------------------------------------------------------------------------
// Direct 2D Toeplitz conv + gating:
//   y[b,p,q,c] = sum_{i,j} A[p-i+13][q-j+13][c] * v[b,i,j,c]
//   g[b,p,q,c] = u[b,p,q,c] * y[b,p,q,c]
// block = (channel-group of 32, batch b); 448 threads = 32 ch x 14 p-rows.
__global__ __launch_bounds__(448) void k_conv(const bf16* __restrict__ v,
                                              const float* __restrict__ Ab,
                                              const bf16* __restrict__ u,
                                              bf16* __restrict__ g) {
    const int cg = blockIdx.x;   // 0..31
    const int b  = blockIdx.y;   // 0..63
    const int tid = threadIdx.x;
    const int c = tid & 31;      // local channel
    const int p = tid >> 5;      // output row 0..13

    __shared__ float vs[196][32];   // v[b, i, j, cg*32+c] as fp32
    for (int idx = tid; idx < 196 * 32; idx += 448) {
        int ij = idx >> 5, cc = idx & 31;
        vs[ij][cc] = __bfloat162float(v[((size_t)b * 196 + ij) * 1024 + cg * 32 + cc]);
    }
    __syncthreads();

    float acc[14] = {};
    for (int i = 0; i < 14; ++i) {
        int dr = p - i + 13;                 // 0..26
        float vv[14];
        #pragma unroll
        for (int j = 0; j < 14; ++j) vv[j] = vs[i * 14 + j][c];
        const float* Arow = Ab + ((size_t)dr * 27) * 1024 + cg * 32 + c;
        #pragma unroll
        for (int dk = 0; dk < 27; ++dk) {    // dk = q - j + 13
            float a = Arow[(size_t)dk * 1024];
            #pragma unroll
            for (int q = 0; q < 14; ++q) {
                int j = q - dk + 13;
                if (j >= 0 && j < 14)        // compile-time after unroll
                    acc[q] = fmaf(a, vv[j], acc[q]);
            }
        }
    }

    #pragma unroll
    for (int q = 0; q < 14; ++q) {
        size_t idx = ((size_t)b * 196 + p * 14 + q) * 1024 + cg * 32 + c;
        g[idx] = __float2bfloat16(acc[q] * __bfloat162float(u[idx]));
    }
}

// ---------------------------------------------------------------------------
extern "C" void kernel_launch(void* const* d_in, const int* in_sizes, int n_in,
                              void* d_out, int out_size, void* d_ws, size_t ws_size,
                              hipStream_t stream) {
    const float* x    = (const float*)d_in[0];
    // d_in[1], d_in[2] = H, W (unused by the op)
    const float* Wu   = (const float*)d_in[3];
    const float* bu   = (const float*)d_in[4];
    const float* Wv   = (const float*)d_in[5];
    const float* bv   = (const float*)d_in[6];
    const float* Wo   = (const float*)d_in[7];
    const float* bo   = (const float*)d_in[8];
    const float* rpw  = (const float*)d_in[9];
    const float* rpb  = (const float*)d_in[10];
    const float* w1   = (const float*)d_in[11];
    const float* b1   = (const float*)d_in[12];
    const float* w2   = (const float*)d_in[13];
    const float* b2   = (const float*)d_in[14];
    const float* w3   = (const float*)d_in[15];
    const float* b3   = (const float*)d_in[16];
    const float* wOut = (const float*)d_in[17];
    const float* bOut = (const float*)d_in[18];

    // Workspace layout (bytes): total ~84.6 MB
    const size_t SZ_R = (size_t)RPOS * 512 * 4;     // 1,492,992
    char* ws = (char*)d_ws;
    float* rA = (float*)(ws);
    float* rB = (float*)(ws + SZ_R);
    float* rn = (float*)(ws + 2 * SZ_R);
    float* Ab = (float*)(ws + 3 * SZ_R);            // 729 x 1024 fp32
    bf16*  ub = (bf16*)(ws + 3 * SZ_R + (size_t)RPOS * 1024 * 4);
    bf16*  vb = ub + (size_t)ROWS * DD1;
    bf16*  gb = vb + (size_t)ROWS * DD1;

    // --- RPE MLP (tiny) ---
    k_rpe_pos<<<RPOS, 256, 0, stream>>>(rpw, rpb, rA);
    k_rmsnorm_relu<<<RPOS, 256, 0, stream>>>(rA, rn);
    k_gemm<float, 0, float><<<dim3(8, 12), 256, 0, stream>>>(rn, w1, b1, rB, RPOS, 512, 512);
    k_rmsnorm_relu<<<RPOS, 256, 0, stream>>>(rB, rn);
    k_gemm<float, 0, float><<<dim3(8, 12), 256, 0, stream>>>(rn, w2, b2, rA, RPOS, 512, 512);
    k_rmsnorm_relu<<<RPOS, 256, 0, stream>>>(rA, rn);
    k_gemm<float, 0, float><<<dim3(8, 12), 256, 0, stream>>>(rn, w3, b3, rB, RPOS, 512, 512);
    k_rmsnorm_relu<<<RPOS, 256, 0, stream>>>(rB, rn);
    // final layer + decay -> Toeplitz coefficients A[729][1024]
    k_gemm<float, 2, float><<<dim3(16, 12), 256, 0, stream>>>(rn, wOut, bOut, Ab, RPOS, 1024, 512);

    // --- u = silu(x@Wu+bu), v = silu(x@Wv+bv)  (bf16 in ws) ---
    k_gemm<float, 1, bf16><<<dim3(16, 196), 256, 0, stream>>>(x, Wu, bu, ub, ROWS, 1024, 512);
    k_gemm<float, 1, bf16><<<dim3(16, 196), 256, 0, stream>>>(x, Wv, bv, vb, ROWS, 1024, 512);

    // --- y = Toeplitz2D(v, A);  g = u * y ---
    k_conv<<<dim3(32, 64), 448, 0, stream>>>(vb, Ab, ub, gb);

    // --- out = g @ Wo + bo ---
    k_gemm<bf16, 0, float><<<dim3(8, 196), 256, 0, stream>>>(gb, Wo, bo, (float*)d_out, ROWS, 512, 1024);
}

// Round 2
// 432.342 us; speedup vs baseline: 2.4334x; 2.4334x over previous
//
#include <hip/hip_runtime.h>
#include <hip/hip_bf16.h>

typedef __hip_bfloat16 bf16;
typedef __attribute__((ext_vector_type(8))) short bf16x8;
typedef __attribute__((ext_vector_type(4))) float f32x4;

// Problem constants: B=64, n=m=14, E=512, D1=1024, heads=8
constexpr int NB    = 64;
constexpr int EE    = 512;
constexpr int DD1   = 1024;
constexpr int RPOS  = 27 * 27;       // 729
constexpr int ROWS  = NB * 14 * 14;  // 12544

#define RMS_EPS 1e-6f
#define GAMMA_LOG2 (-0.00144344319f)   // log2(0.999)

__device__ __forceinline__ float ldf(const float* p)  { return *p; }
__device__ __forceinline__ float ldf(const bf16* p)   { return __bfloat162float(*p); }
__device__ __forceinline__ void  stf(float* p, float v) { *p = v; }
__device__ __forceinline__ void  stf(bf16* p, float v)  { *p = __float2bfloat16(v); }

__device__ __forceinline__ void gload_lds16(const bf16* g, bf16* l) {
    __builtin_amdgcn_global_load_lds(
        (const __attribute__((address_space(1))) void*)g,
        (__attribute__((address_space(3))) void*)l, 16, 0, 0);
}

// ---------------------------------------------------------------------------
__global__ void k_rpe_pos(const float* __restrict__ w, const float* __restrict__ bias,
                          float* __restrict__ out) {
    int p = blockIdx.x;
    float ii = (float)(p / 27 - 13);
    float jj = (float)(p % 27 - 13);
    for (int c = threadIdx.x; c < 512; c += 256)
        out[p * 512 + c] = ii * w[c] + jj * w[512 + c] + bias[c];
}

// ---------------------------------------------------------------------------
__global__ void k_rmsnorm_relu(const float* __restrict__ in, float* __restrict__ out) {
    int r = blockIdx.x;
    const float* x = in + (size_t)r * 512;
    float v0 = x[threadIdx.x];
    float v1 = x[threadIdx.x + 256];
    float s = v0 * v0 + v1 * v1;
    #pragma unroll
    for (int off = 32; off; off >>= 1) s += __shfl_down(s, off, 64);
    __shared__ float ps[4];
    if ((threadIdx.x & 63) == 0) ps[threadIdx.x >> 6] = s;
    __syncthreads();
    float tot = ps[0] + ps[1] + ps[2] + ps[3];
    float scale = rsqrtf(tot * (1.0f / 512.0f) + RMS_EPS);
    out[(size_t)r * 512 + threadIdx.x]       = fmaxf(v0 * scale, 0.0f);
    out[(size_t)r * 512 + threadIdx.x + 256] = fmaxf(v1 * scale, 0.0f);
}

// ---------------------------------------------------------------------------
// VALU GEMM (kept for the small RPE chain only).
// EPI: 0 = none, 2 = Toeplitz decay gamma^(|i-13|+|j-13|) by row
template <typename TA, int EPI, typename TO>
__global__ __launch_bounds__(256) void k_gemm(const TA* __restrict__ A,
                                              const float* __restrict__ Bw,
                                              const float* __restrict__ bias,
                                              TO* __restrict__ out,
                                              int Mr, int Nc, int Kd) {
    __shared__ float As[16][64];
    __shared__ float Bs[16][64];
    const int m0 = blockIdx.y * 64;
    const int n0 = blockIdx.x * 64;
    const int tid = threadIdx.x;
    const int tr = tid >> 4;
    const int tc = tid & 15;

    float acc[4][4] = {};

    for (int k0 = 0; k0 < Kd; k0 += 16) {
        #pragma unroll
        for (int l = 0; l < 4; ++l) {
            int idx = tid + l * 256;
            int m = idx >> 4, k = idx & 15;
            int gm = m0 + m;
            float val = (gm < Mr) ? ldf(&A[(size_t)gm * Kd + k0 + k]) : 0.0f;
            As[k][m] = val;
        }
        #pragma unroll
        for (int l = 0; l < 4; ++l) {
            int idx = tid + l * 256;
            int k = idx >> 6, n = idx & 63;
            Bs[k][n] = Bw[(size_t)(k0 + k) * Nc + n0 + n];
        }
        __syncthreads();
        #pragma unroll
        for (int kk = 0; kk < 16; ++kk) {
            float4 a4 = *(const float4*)&As[kk][tr * 4];
            float4 b4 = *(const float4*)&Bs[kk][tc * 4];
            float av[4] = {a4.x, a4.y, a4.z, a4.w};
            float bv[4] = {b4.x, b4.y, b4.z, b4.w};
            #pragma unroll
            for (int r = 0; r < 4; ++r)
                #pragma unroll
                for (int c = 0; c < 4; ++c)
                    acc[r][c] = fmaf(av[r], bv[c], acc[r][c]);
        }
        __syncthreads();
    }

    #pragma unroll
    for (int r = 0; r < 4; ++r) {
        int row = m0 + tr * 4 + r;
        if (row >= Mr) break;
        float decay = 1.0f;
        if (EPI == 2) {
            int i = row / 27, j = row % 27;
            float dist = (float)(abs(i - 13) + abs(j - 13));
            decay = exp2f(dist * GAMMA_LOG2);
        }
        #pragma unroll
        for (int c = 0; c < 4; ++c) {
            int col = n0 + tc * 4 + c;
            float val = acc[r][c] + bias[col];
            if (EPI == 2) val *= decay;
            stf(&out[(size_t)row * Nc + col], val);
        }
    }
}

// ---------------------------------------------------------------------------
// MFMA bf16 GEMM, m97 structure: 128x128 tile, BK=32, 4 waves, 4x4 frags/wave.
// A[M][lda] bf16 row-major, Bt[N][K] bf16 (B transposed), out row stride ldo.
// EPI: 0 = bias only, 1 = silu(bias+acc)
template <int EPI, typename TO>
__global__ __launch_bounds__(256) void k_mgemm(const bf16* __restrict__ A, int lda,
                                               const bf16* __restrict__ Bt,
                                               const float* __restrict__ bias,
                                               TO* __restrict__ out, int ldo,
                                               int M, int N, int K) {
    __shared__ bf16 As[128 * 32];
    __shared__ bf16 Bs[128 * 32];
    const int tid = threadIdx.x;
    const int m0 = blockIdx.y * 128;
    const int n0 = blockIdx.x * 128;
    const int lane = tid & 63;
    const int w = tid >> 6;
    const int wr = (w >> 1) * 64;
    const int wc = (w & 1) * 64;
    const int lr = lane & 15;
    const int lk = (lane >> 4) * 8;

    f32x4 acc[4][4] = {};

    for (int k0 = 0; k0 < K; k0 += 32) {
        #pragma unroll
        for (int t = 0; t < 2; ++t) {
            int flat = t * 256 + tid;            // 0..511
            int row = flat >> 2;                 // 0..127
            int seg = (flat & 3) * 8;            // k sub-offset
            gload_lds16(&A[(size_t)(m0 + row) * lda + k0 + seg], &As[flat * 8]);
            gload_lds16(&Bt[(size_t)(n0 + row) * K + k0 + seg], &Bs[flat * 8]);
        }
        __syncthreads();
        bf16x8 af[4], bf[4];
        #pragma unroll
        for (int i = 0; i < 4; ++i) {
            af[i] = *(const bf16x8*)&As[(wr + i * 16 + lr) * 32 + lk];
            bf[i] = *(const bf16x8*)&Bs[(wc + i * 16 + lr) * 32 + lk];
        }
        #pragma unroll
        for (int i = 0; i < 4; ++i)
            #pragma unroll
            for (int j = 0; j < 4; ++j)
                acc[i][j] = __builtin_amdgcn_mfma_f32_16x16x32_bf16(af[i], bf[j], acc[i][j], 0, 0, 0);
        __syncthreads();
    }

    // C/D layout: col = lane&15, row = (lane>>4)*4 + r   [m89/m91-verified]
    const int crow = (lane >> 4) * 4;
    const int ccol = lane & 15;
    #pragma unroll
    for (int i = 0; i < 4; ++i)
        #pragma unroll
        for (int j = 0; j < 4; ++j) {
            int gc = n0 + wc + j * 16 + ccol;
            float bb = bias[gc];
            #pragma unroll
            for (int r = 0; r < 4; ++r) {
                int gr = m0 + wr + i * 16 + crow + r;
                float val = acc[i][j][r] + bb;
                if (EPI == 1) val = val / (1.0f + expf(-val));
                stf(&out[(size_t)gr * ldo + gc], val);
            }
        }
}

// ---------------------------------------------------------------------------
// fp32 [R][C] -> bf16 [C][R] transpose (weights prep)
__global__ __launch_bounds__(256) void k_transpose(const float* __restrict__ src,
                                                   bf16* __restrict__ dst, int R, int C) {
    __shared__ float t[32][33];
    int bx = blockIdx.x * 32;  // C offset
    int by = blockIdx.y * 32;  // R offset
    int tx = threadIdx.x & 31, ty = threadIdx.x >> 5;  // ty 0..7
    #pragma unroll
    for (int i = 0; i < 4; ++i)
        t[ty + i * 8][tx] = src[(size_t)(by + ty + i * 8) * C + bx + tx];
    __syncthreads();
    #pragma unroll
    for (int i = 0; i < 4; ++i)
        dst[(size_t)(bx + ty + i * 8) * R + by + tx] = __float2bfloat16(t[tx][ty + i * 8]);
}

// ---------------------------------------------------------------------------
__global__ void k_cvt_bf16(const float* __restrict__ src, bf16* __restrict__ dst, int n4) {
    int i = blockIdx.x * blockDim.x + threadIdx.x;
    if (i < n4) {
        float4 v = *(const float4*)&src[i * 4];
        bf16* d = &dst[i * 4];
        d[0] = __float2bfloat16(v.x);
        d[1] = __float2bfloat16(v.y);
        d[2] = __float2bfloat16(v.z);
        d[3] = __float2bfloat16(v.w);
    }
}

__global__ void k_bias_uv(const float* __restrict__ bu, const float* __restrict__ bv,
                          float* __restrict__ dst) {
    int c = blockIdx.x * 256 + threadIdx.x;
    if (c < 2048) dst[c] = (c < 1024) ? bu[c] : bv[c - 1024];
}

// ---------------------------------------------------------------------------
// Direct 2D Toeplitz conv + gating, in place over the v half of uv:
//   y[b,p,q,c] = sum_{i,j} A[p-i+13][q-j+13][c] * v[b,i,j,c]
//   g = u * y  (written over v)
// uv layout: [b*196+pos][2048], u = cols 0..1023, v = cols 1024..2047
__global__ __launch_bounds__(448) void k_conv(bf16* __restrict__ uv,
                                              const float* __restrict__ Ab) {
    const int cg = blockIdx.x;   // 0..31 channel group
    const int b  = blockIdx.y;   // 0..63
    const int tid = threadIdx.x;
    const int c = tid & 31;
    const int p = tid >> 5;      // 0..13

    __shared__ float vs[196][32];
    for (int idx = tid; idx < 196 * 32; idx += 448) {
        int ij = idx >> 5, cc = idx & 31;
        vs[ij][cc] = __bfloat162float(uv[((size_t)b * 196 + ij) * 2048 + 1024 + cg * 32 + cc]);
    }
    __syncthreads();

    float acc[14] = {};
    for (int i = 0; i < 14; ++i) {
        int dr = p - i + 13;                 // 0..26
        float vv[14];
        #pragma unroll
        for (int j = 0; j < 14; ++j) vv[j] = vs[i * 14 + j][c];
        const float* Arow = Ab + ((size_t)dr * 27) * 1024 + cg * 32 + c;
        #pragma unroll
        for (int dk = 0; dk < 27; ++dk) {    // dk = q - j + 13
            float a = Arow[(size_t)dk * 1024];
            #pragma unroll
            for (int q = 0; q < 14; ++q) {
                int j = q - dk + 13;
                if (j >= 0 && j < 14)
                    acc[q] = fmaf(a, vv[j], acc[q]);
            }
        }
    }

    #pragma unroll
    for (int q = 0; q < 14; ++q) {
        size_t base = ((size_t)b * 196 + p * 14 + q) * 2048 + cg * 32 + c;
        float uu = __bfloat162float(uv[base]);
        uv[base + 1024] = __float2bfloat16(acc[q] * uu);
    }
}

// ---------------------------------------------------------------------------
extern "C" void kernel_launch(void* const* d_in, const int* in_sizes, int n_in,
                              void* d_out, int out_size, void* d_ws, size_t ws_size,
                              hipStream_t stream) {
    const float* x    = (const float*)d_in[0];
    const float* Wu   = (const float*)d_in[3];
    const float* bu   = (const float*)d_in[4];
    const float* Wv   = (const float*)d_in[5];
    const float* bv   = (const float*)d_in[6];
    const float* Wo   = (const float*)d_in[7];
    const float* bo   = (const float*)d_in[8];
    const float* rpw  = (const float*)d_in[9];
    const float* rpb  = (const float*)d_in[10];
    const float* w1   = (const float*)d_in[11];
    const float* b1   = (const float*)d_in[12];
    const float* w2   = (const float*)d_in[13];
    const float* b2   = (const float*)d_in[14];
    const float* w3   = (const float*)d_in[15];
    const float* b3   = (const float*)d_in[16];
    const float* wOut = (const float*)d_in[17];
    const float* bOut = (const float*)d_in[18];

    // Workspace layout (~75 MB)
    char* ws = (char*)d_ws;
    size_t off = 0;
    auto take = [&](size_t bytes) { char* p = ws + off; off += (bytes + 255) & ~size_t(255); return p; };
    float* rA     = (float*)take((size_t)RPOS * 512 * 4);
    float* rB     = (float*)take((size_t)RPOS * 512 * 4);
    float* rn     = (float*)take((size_t)RPOS * 512 * 4);
    float* Ab     = (float*)take((size_t)RPOS * 1024 * 4);
    bf16*  xb     = (bf16*)take((size_t)ROWS * EE * 2);
    bf16*  WuvT   = (bf16*)take((size_t)2048 * 512 * 2);
    bf16*  WoT    = (bf16*)take((size_t)512 * 1024 * 2);
    float* biasUv = (float*)take(2048 * 4);
    bf16*  uvb    = (bf16*)take((size_t)ROWS * 2048 * 2);

    // --- RPE MLP (small, VALU path) ---
    k_rpe_pos<<<RPOS, 256, 0, stream>>>(rpw, rpb, rA);
    k_rmsnorm_relu<<<RPOS, 256, 0, stream>>>(rA, rn);
    k_gemm<float, 0, float><<<dim3(8, 12), 256, 0, stream>>>(rn, w1, b1, rB, RPOS, 512, 512);
    k_rmsnorm_relu<<<RPOS, 256, 0, stream>>>(rB, rn);
    k_gemm<float, 0, float><<<dim3(8, 12), 256, 0, stream>>>(rn, w2, b2, rA, RPOS, 512, 512);
    k_rmsnorm_relu<<<RPOS, 256, 0, stream>>>(rA, rn);
    k_gemm<float, 0, float><<<dim3(8, 12), 256, 0, stream>>>(rn, w3, b3, rB, RPOS, 512, 512);
    k_rmsnorm_relu<<<RPOS, 256, 0, stream>>>(rB, rn);
    k_gemm<float, 2, float><<<dim3(16, 12), 256, 0, stream>>>(rn, wOut, bOut, Ab, RPOS, 1024, 512);

    // --- prep: x->bf16, W->bf16 transposed, bias concat ---
    k_cvt_bf16<<<(ROWS * EE / 4 + 255) / 256, 256, 0, stream>>>(x, xb, ROWS * EE / 4);
    k_transpose<<<dim3(32, 16), 256, 0, stream>>>(Wu, WuvT, 512, 1024);
    k_transpose<<<dim3(32, 16), 256, 0, stream>>>(Wv, WuvT + (size_t)1024 * 512, 512, 1024);
    k_transpose<<<dim3(16, 32), 256, 0, stream>>>(Wo, WoT, 1024, 512);
    k_bias_uv<<<8, 256, 0, stream>>>(bu, bv, biasUv);

    // --- uv = silu(x @ [Wu|Wv] + [bu|bv])  (MFMA, fused) ---
    k_mgemm<1, bf16><<<dim3(16, 98), 256, 0, stream>>>(xb, 512, WuvT, biasUv, uvb, 2048,
                                                       ROWS, 2048, 512);

    // --- y = Toeplitz2D(v, A); g = u*y written over v ---
    k_conv<<<dim3(32, 64), 448, 0, stream>>>(uvb, Ab);

    // --- out = g @ Wo + bo  (MFMA) ---
    k_mgemm<0, float><<<dim3(4, 98), 256, 0, stream>>>(uvb + 1024, 2048, WoT, bo,
                                                       (float*)d_out, 512, ROWS, 512, 1024);
}